// Round 12
// baseline (193.299 us; speedup 1.0000x reference)
//
#include <hip/hip_runtime.h>
#include <hip/hip_fp16.h>

// GCN: 3x GCNConv(relu) + global_mean_pool + linear head.
//   k_bin:  bucket edges by dst (LDS-staged, BCHUNK=4096).
//   k_csr:  bucket-total scan + histogram + LDS scan -> rowptr/dinv + place
//           + fused k_bounds + fused wconv (blocks 196..198).
//   k_gmfma_x/h: g = f16(dinv*(in@W)) via mfma_f32_16x16x32_f16.
//   k_agg2: half-wave-per-node gather, PAIRED-ROW dwordx2: lane=(s,c4) loads
//           8B of virtual row 2t+s -> 2 rows per load instruction; whole
//           <=32-row neighborhood (self = virtual row 0) in ONE 16-deep
//           masked batch; shfl_xor(16) merges parities. Halves loads+shfls
//           vs R11's per-dword scheme.
// Pool: 512-thr block-per-graph segmented mean + fused 64x32 head.

#define CH 64
#define OC 32

#define BINW 512
#define NBK  196         // ceil(100000/512); valid for N <= 100352
#define BIN_CAP 56       // mean 4096/196 = 20.9 per bucket per chunk
#define BCHUNK 4096
#define GCAP 10240       // per-bucket cap (mean 8163, +23 sigma)

typedef unsigned int u32;
typedef _Float16 f16;
typedef __attribute__((ext_vector_type(8))) _Float16 f16x8;
typedef __attribute__((ext_vector_type(4))) float f32x4;

__device__ __forceinline__ float2 upk(u32 u) {
    __half2 h = *reinterpret_cast<__half2*>(&u);
    return __half22float2(h);
}
__device__ __forceinline__ u32 pk2(float x, float y) {
    __half2 h = __floats2half2_rn(x, y);
    return *reinterpret_cast<u32*>(&h);
}

// ---- pass 1: bin edges by dst into bucket arrays (LDS-staged) -----------
__global__ __launch_bounds__(256) void k_bin(const int* __restrict__ src, const int* __restrict__ dst,
                                             u32* __restrict__ gbuf, int* __restrict__ gcur, int E) {
    __shared__ u32 lst[NBK][BIN_CAP];
    __shared__ int lcnt[NBK];
    __shared__ int lbase[NBK];
    int tid = threadIdx.x;
    for (int i = tid; i < NBK; i += 256) lcnt[i] = 0;
    __syncthreads();
    int beg = blockIdx.x * BCHUNK;
    int end = min(beg + BCHUNK, E);
    for (int e = beg + tid; e < end; e += 256) {
        int d = dst[e];
        u32 u = (u32)src[e] | ((u32)(d & (BINW - 1)) << 17);
        int b = d >> 9;
        int p = atomicAdd(&lcnt[b], 1);
        if (p < BIN_CAP) lst[b][p] = u;
        else {
            int gp = atomicAdd(&gcur[b], 1);
            if (gp < GCAP) gbuf[(size_t)b * GCAP + gp] = u;
        }
    }
    __syncthreads();
    for (int b = tid; b < NBK; b += 256) {
        int c = min(lcnt[b], BIN_CAP);
        lbase[b] = atomicAdd(&gcur[b], c);
        lcnt[b] = c;
    }
    __syncthreads();
    int wid = tid >> 6, lane = tid & 63;
    for (int b = wid; b < NBK; b += 4) {
        int c = lcnt[b], base = lbase[b];
        for (int i = lane; i < c; i += 64)
            gbuf[(size_t)b * GCAP + base + i] = lst[b][i];
    }
}

// ---- CSR + bounds + wconv, one dispatch ---------------------------------
__global__ __launch_bounds__(512) void k_csr(const u32* __restrict__ gbuf, const int* __restrict__ gcur,
                                             int* __restrict__ rowptr, float* __restrict__ dinv,
                                             int* __restrict__ col, int N,
                                             const int* __restrict__ batch, int* __restrict__ gstart, int ngraphs,
                                             const float* __restrict__ W1, const float* __restrict__ W2,
                                             const float* __restrict__ W3, f16* __restrict__ Wpk) {
    int b = blockIdx.x, tid = threadIdx.x;
    if (b >= NBK) {                                 // ---- wconv blocks ----
        const float* Ws[3] = {W1, W2, W3};
        const float* W = Ws[b - NBK];
        int i = tid >> 6, l = tid & 63;
        int s = i & 1, t4 = i >> 1;
        int kbase = s * 32 + ((l >> 4) * 8);
        int cc = t4 * 16 + (l & 15);
        f16* dstp = Wpk + (((size_t)(b - NBK) * 8 + i) * 64 + l) * 8;
#pragma unroll
        for (int j = 0; j < 8; j++) dstp[j] = (f16)W[(kbase + j) * 64 + cc];
        return;
    }
    __shared__ int h[BINW];
    __shared__ int sc[BINW];
    __shared__ int bb[256];
    if (tid < 256) bb[tid] = (tid < NBK) ? min(gcur[tid], GCAP) : 0;
    __syncthreads();
    for (int o = 1; o < 256; o <<= 1) {
        int add = (tid < 256 && tid >= o) ? bb[tid - o] : 0;
        __syncthreads();
        if (tid < 256) bb[tid] += add;
        __syncthreads();
    }
    int my_base = (b == 0) ? 0 : bb[b - 1];
    if (b == 0 && tid == 0) rowptr[N] = bb[NBK - 1];
    h[tid] = 0;
    __syncthreads();
    int c = min(gcur[b], GCAP);
    const u32* p = gbuf + (size_t)b * GCAP;
    for (int i = tid; i < c; i += 512) atomicAdd(&h[p[i] >> 17], 1);
    __syncthreads();
    int cnt = h[tid];
    sc[tid] = cnt;
    __syncthreads();
    for (int o = 1; o < BINW; o <<= 1) {
        int add = (tid >= o) ? sc[tid - o] : 0;
        __syncthreads();
        sc[tid] += add;
        __syncthreads();
    }
    int ex = my_base + sc[tid] - cnt;
    int node = b * BINW + tid;
    if (node < N) {
        rowptr[node] = ex;
        dinv[node] = rsqrtf((float)(cnt + 1));     // degree includes self-loop
        int bat = batch[node];
        int prev = (node == 0) ? -1 : batch[node - 1];
        for (int g = prev + 1; g <= bat; g++) gstart[g] = node;
        if (node == N - 1) for (int g = bat + 1; g <= ngraphs; g++) gstart[g] = N;
    }
    h[tid] = ex;
    __syncthreads();
    for (int i = tid; i < c; i += 512) {
        u32 u = p[i];
        int pos = atomicAdd(&h[u >> 17], 1);
        col[pos] = (int)(u & 0x1FFFF);
    }
}

// ---- MFMA gemm, f32 input (layer 1): g = f16(dinv * (x @ W)) ------------
__global__ __launch_bounds__(256) void k_gmfma_x(const float* __restrict__ in, const f16x8* __restrict__ Wpk,
                                                 const float* __restrict__ dinv, f16* __restrict__ out, int n_nodes) {
    int lane = threadIdx.x & 63;
    int wv = blockIdx.x * 4 + (threadIdx.x >> 6);
    int ntiles = (n_nodes + 15) >> 4;
    if (wv >= ntiles) return;
    f16x8 bf[8];
#pragma unroll
    for (int i = 0; i < 8; i++) bf[i] = Wpk[i * 64 + lane];
    int r0 = lane & 15;
    int kc = (lane >> 4) * 8;
    int n0 = wv * 16;
    int ar = min(n0 + r0, n_nodes - 1);
    const float* arow = in + (size_t)ar * CH + kc;
    float4 p0 = *(const float4*)(arow);
    float4 p1 = *(const float4*)(arow + 4);
    float4 q0 = *(const float4*)(arow + 32);
    float4 q1 = *(const float4*)(arow + 36);
    float pa[8] = {p0.x, p0.y, p0.z, p0.w, p1.x, p1.y, p1.z, p1.w};
    float qa[8] = {q0.x, q0.y, q0.z, q0.w, q1.x, q1.y, q1.z, q1.w};
    f16x8 a0, a1;
#pragma unroll
    for (int j = 0; j < 8; j++) { a0[j] = (f16)pa[j]; a1[j] = (f16)qa[j]; }
    f32x4 z = {0.f, 0.f, 0.f, 0.f};
    f32x4 acc0 = z, acc1 = z, acc2 = z, acc3 = z;
    acc0 = __builtin_amdgcn_mfma_f32_16x16x32_f16(a0, bf[0], acc0, 0, 0, 0);
    acc0 = __builtin_amdgcn_mfma_f32_16x16x32_f16(a1, bf[1], acc0, 0, 0, 0);
    acc1 = __builtin_amdgcn_mfma_f32_16x16x32_f16(a0, bf[2], acc1, 0, 0, 0);
    acc1 = __builtin_amdgcn_mfma_f32_16x16x32_f16(a1, bf[3], acc1, 0, 0, 0);
    acc2 = __builtin_amdgcn_mfma_f32_16x16x32_f16(a0, bf[4], acc2, 0, 0, 0);
    acc2 = __builtin_amdgcn_mfma_f32_16x16x32_f16(a1, bf[5], acc2, 0, 0, 0);
    acc3 = __builtin_amdgcn_mfma_f32_16x16x32_f16(a0, bf[6], acc3, 0, 0, 0);
    acc3 = __builtin_amdgcn_mfma_f32_16x16x32_f16(a1, bf[7], acc3, 0, 0, 0);
    int rb = n0 + (lane >> 4) * 4;
    float4 dv = *(const float4*)(dinv + rb);
    float dva[4] = {dv.x, dv.y, dv.z, dv.w};
#pragma unroll
    for (int r = 0; r < 4; r++) {
        int nn = rb + r;
        if (nn < n_nodes) {
            f16* orow = out + (size_t)nn * CH + r0;
            orow[0]  = (f16)(acc0[r] * dva[r]);
            orow[16] = (f16)(acc1[r] * dva[r]);
            orow[32] = (f16)(acc2[r] * dva[r]);
            orow[48] = (f16)(acc3[r] * dva[r]);
        }
    }
}

// ---- MFMA gemm, f16 input: g = f16(dinv * (h @ W)) ----------------------
__global__ __launch_bounds__(256) void k_gmfma_h(const f16* __restrict__ in, const f16x8* __restrict__ Wpk,
                                                 const float* __restrict__ dinv, f16* __restrict__ out, int n_nodes) {
    int lane = threadIdx.x & 63;
    int wv = blockIdx.x * 4 + (threadIdx.x >> 6);
    int ntiles = (n_nodes + 15) >> 4;
    if (wv >= ntiles) return;
    f16x8 bf[8];
#pragma unroll
    for (int i = 0; i < 8; i++) bf[i] = Wpk[i * 64 + lane];
    int r0 = lane & 15;
    int kc = (lane >> 4) * 8;
    int n0 = wv * 16;
    int ar = min(n0 + r0, n_nodes - 1);
    const f16* arow = in + (size_t)ar * CH + kc;
    f16x8 a0 = *(const f16x8*)(arow);
    f16x8 a1 = *(const f16x8*)(arow + 32);
    f32x4 z = {0.f, 0.f, 0.f, 0.f};
    f32x4 acc0 = z, acc1 = z, acc2 = z, acc3 = z;
    acc0 = __builtin_amdgcn_mfma_f32_16x16x32_f16(a0, bf[0], acc0, 0, 0, 0);
    acc0 = __builtin_amdgcn_mfma_f32_16x16x32_f16(a1, bf[1], acc0, 0, 0, 0);
    acc1 = __builtin_amdgcn_mfma_f32_16x16x32_f16(a0, bf[2], acc1, 0, 0, 0);
    acc1 = __builtin_amdgcn_mfma_f32_16x16x32_f16(a1, bf[3], acc1, 0, 0, 0);
    acc2 = __builtin_amdgcn_mfma_f32_16x16x32_f16(a0, bf[4], acc2, 0, 0, 0);
    acc2 = __builtin_amdgcn_mfma_f32_16x16x32_f16(a1, bf[5], acc2, 0, 0, 0);
    acc3 = __builtin_amdgcn_mfma_f32_16x16x32_f16(a0, bf[6], acc3, 0, 0, 0);
    acc3 = __builtin_amdgcn_mfma_f32_16x16x32_f16(a1, bf[7], acc3, 0, 0, 0);
    int rb = n0 + (lane >> 4) * 4;
    float4 dv = *(const float4*)(dinv + rb);
    float dva[4] = {dv.x, dv.y, dv.z, dv.w};
#pragma unroll
    for (int r = 0; r < 4; r++) {
        int nn = rb + r;
        if (nn < n_nodes) {
            f16* orow = out + (size_t)nn * CH + r0;
            orow[0]  = (f16)(acc0[r] * dva[r]);
            orow[16] = (f16)(acc1[r] * dva[r]);
            orow[32] = (f16)(acc2[r] * dva[r]);
            orow[48] = (f16)(acc3[r] * dva[r]);
        }
    }
}

// ---- half-wave-per-node gather, paired-row dwordx2 ----------------------
// Half-lane hl = (s = hl>>4, c4 = hl&15). Virtual rows: 0 = self, 1..deg =
// neighbors. Lane loads uint2 (channels 4c4..4c4+3) of row 2t+s -> 2 rows
// per load instruction; one masked 16-deep batch covers <=32 rows.
// shfl_xor(16) merges parities; s==0 lanes apply dinv/bias/relu and store.
__global__ __launch_bounds__(512) void k_agg2(const u32* __restrict__ g, const int* __restrict__ rowptr,
                                              const int* __restrict__ col, const float* __restrict__ dinv,
                                              const float* __restrict__ bias, u32* __restrict__ h, int n_nodes) {
    int hl = threadIdx.x & 31;
    int s = hl >> 4;
    int c4 = hl & 15;
    int node = (blockIdx.x * 512 + threadIdx.x) >> 5;
    if (node >= n_nodes) return;
    int beg = rowptr[node], end = rowptr[node + 1];
    int deg = end - beg;
    int nv = min(deg + 1, 32);                       // virtual rows
    // position hl -> row id (clamped; deg==0 -> all read self, masked to 0)
    int vi = (hl == 0 || deg == 0) ? node : col[beg + min(hl, deg) - 1];
    u32 lo[16], hi[16];
#pragma unroll
    for (int t = 0; t < 16; t++) {
        int j = __shfl(vi, 2 * t + s, 32);
        uint2 v = *(const uint2*)(g + (size_t)j * 32 + c4 * 2);
        lo[t] = v.x; hi[t] = v.y;
    }
    float a0 = 0.f, a1 = 0.f, a2 = 0.f, a3 = 0.f;
#pragma unroll
    for (int t = 0; t < 16; t++) {
        bool ok = (2 * t + s) < nv;
        float2 f0 = upk(ok ? lo[t] : 0u);
        float2 f1 = upk(ok ? hi[t] : 0u);
        a0 += f0.x; a1 += f0.y; a2 += f1.x; a3 += f1.y;
    }
    for (int i = 32; i <= deg; i++) {                // rare: deg > 31
        if (s == 0) {
            uint2 v = *(const uint2*)(g + (size_t)col[beg + i - 1] * 32 + c4 * 2);
            float2 f0 = upk(v.x), f1 = upk(v.y);
            a0 += f0.x; a1 += f0.y; a2 += f1.x; a3 += f1.y;
        }
    }
    a0 += __shfl_xor(a0, 16, 32);
    a1 += __shfl_xor(a1, 16, 32);
    a2 += __shfl_xor(a2, 16, 32);
    a3 += __shfl_xor(a3, 16, 32);
    if (s == 0) {
        float dn = dinv[node];
        float4 bb = *(const float4*)(bias + 4 * c4);
        uint2 wv;
        wv.x = pk2(fmaxf(fmaf(dn, a0, bb.x), 0.f), fmaxf(fmaf(dn, a1, bb.y), 0.f));
        wv.y = pk2(fmaxf(fmaf(dn, a2, bb.z), 0.f), fmaxf(fmaf(dn, a3, bb.w), 0.f));
        *(uint2*)(h + (size_t)node * 32 + c4 * 2) = wv;
    }
}

// ---- fused mean-pool + head: 512-thr block per graph --------------------
__global__ __launch_bounds__(512) void k_pool_head(const u32* __restrict__ h, const int* __restrict__ gstart,
                                                   const float* __restrict__ Wl, const float* __restrict__ bl,
                                                   float* __restrict__ out) {
    __shared__ float part[16][CH];
    __shared__ float mean[CH];
    int gg = blockIdx.x;
    int hw = threadIdx.x >> 5;
    int c2 = threadIdx.x & 31;
    int beg = gstart[gg], end = gstart[gg + 1];
    float a0 = 0.f, a1 = 0.f;
    for (int n = beg + hw; n < end; n += 16) {
        float2 f = upk(h[(size_t)n * 32 + c2]);
        a0 += f.x; a1 += f.y;
    }
    part[hw][2 * c2] = a0; part[hw][2 * c2 + 1] = a1;
    __syncthreads();
    if (threadIdx.x < CH) {
        int c = threadIdx.x;
        float s = 0.f;
#pragma unroll
        for (int i = 0; i < 16; i++) s += part[i][c];
        float inv = 1.0f / fmaxf((float)(end - beg), 1.0f);
        mean[c] = s * inv;
    }
    __syncthreads();
    if (threadIdx.x < OC) {
        int o = threadIdx.x;
        float a = bl[o];
#pragma unroll
        for (int c = 0; c < CH; c++) a = fmaf(mean[c], Wl[c * OC + o], a);
        out[gg * OC + o] = a;
    }
}

extern "C" void kernel_launch(void* const* d_in, const int* in_sizes, int n_in,
                              void* d_out, int out_size, void* d_ws, size_t ws_size,
                              hipStream_t stream) {
    const float* x    = (const float*)d_in[0];
    const int*   edge = (const int*)d_in[1];   // [2][E]: src then dst
    const int*   batch= (const int*)d_in[2];
    const float* W1 = (const float*)d_in[3]; const float* b1 = (const float*)d_in[4];
    const float* W2 = (const float*)d_in[5]; const float* b2 = (const float*)d_in[6];
    const float* W3 = (const float*)d_in[7]; const float* b3 = (const float*)d_in[8];
    const float* Wl = (const float*)d_in[9]; const float* bl = (const float*)d_in[10];
    float* out = (float*)d_out;

    const int N  = in_sizes[2];        // 100000 (<= 100352 for NBK=196)
    const int E  = in_sizes[1] / 2;    // 1600000
    const int NG = out_size / OC;      // 128
    const int* src = edge;
    const int* dst = edge + E;

    char* p = (char*)d_ws;
    auto alloc = [&](size_t bytes) -> void* { void* r = p; p += (bytes + 255) & ~(size_t)255; return r; };
    int*   rowptr = (int*)alloc((size_t)(N + 1) * 4);
    int*   col    = (int*)alloc((size_t)E * 4);
    float* dinv   = (float*)alloc((size_t)N * 4);
    int*   gstart = (int*)alloc((size_t)(NG + 1) * 4);
    int*   gcur   = (int*)alloc((size_t)NBK * 4);
    u32*   gbuf   = (u32*)alloc((size_t)NBK * GCAP * 4);
    f16*   Wpk    = (f16*)alloc((size_t)3 * 8 * 64 * 8 * 2);
    u32*   Ga     = (u32*)alloc((size_t)N * CH * 2);
    u32*   Hb     = (u32*)alloc((size_t)N * CH * 2);

    hipMemsetAsync(gcur, 0, (size_t)NBK * 4, stream);

    int nbl2 = (N * 32 + 511) / 512;               // half-wave per node
    int binb = (E + BCHUNK - 1) / BCHUNK;
    int gemb = ((N + 15) / 16 + 3) / 4;            // 4 tiles/block

    k_bin<<<binb, 256, 0, stream>>>(src, dst, gbuf, gcur, E);
    k_csr<<<NBK + 3, 512, 0, stream>>>(gbuf, gcur, rowptr, dinv, col, N,
                                       batch, gstart, NG, W1, W2, W3, Wpk);

    const f16x8* Wp = (const f16x8*)Wpk;
    k_gmfma_x<<<gemb, 256, 0, stream>>>(x, Wp, dinv, (f16*)Ga, N);                     // g1
    k_agg2<<<nbl2, 512, 0, stream>>>(Ga, rowptr, col, dinv, b1, Hb, N);                // h1
    k_gmfma_h<<<gemb, 256, 0, stream>>>((const f16*)Hb, Wp + 8 * 64, dinv, (f16*)Ga, N);   // g2
    k_agg2<<<nbl2, 512, 0, stream>>>(Ga, rowptr, col, dinv, b2, Hb, N);                // h2
    k_gmfma_h<<<gemb, 256, 0, stream>>>((const f16*)Hb, Wp + 16 * 64, dinv, (f16*)Ga, N);  // g3
    k_agg2<<<nbl2, 512, 0, stream>>>(Ga, rowptr, col, dinv, b3, Hb, N);                // h3
    k_pool_head<<<NG, 512, 0, stream>>>(Hb, gstart, Wl, bl, out);
}

// Round 13
// 192.985 us; speedup vs baseline: 1.0016x; 1.0016x over previous
//
#include <hip/hip_runtime.h>
#include <hip/hip_fp16.h>

// GCN: 3x GCNConv(relu) + global_mean_pool + linear head.
//   k_bin:  bucket edges by dst (LDS-staged, BCHUNK=4096).
//   k_csr:  bucket-total scan + histogram + LDS scan -> rowptr/dinv + place
//           + fused k_bounds + fused wconv (blocks 196..198).
//   k_gmfma_x/h: g = f16(dinv*(in@W)) via mfma_f32_16x16x32_f16.
//   k_agg2: half-wave-per-node gather, paired-row dwordx2 (2 rows per load
//           instruction, R12) + CONDITIONAL second half (rows 16..31 only
//           when nv>16, R11) -> R11's byte traffic at half the instructions.
// Pool: 512-thr block-per-graph segmented mean + fused 64x32 head.

#define CH 64
#define OC 32

#define BINW 512
#define NBK  196         // ceil(100000/512); valid for N <= 100352
#define BIN_CAP 56       // mean 4096/196 = 20.9 per bucket per chunk
#define BCHUNK 4096
#define GCAP 10240       // per-bucket cap (mean 8163, +23 sigma)

typedef unsigned int u32;
typedef _Float16 f16;
typedef __attribute__((ext_vector_type(8))) _Float16 f16x8;
typedef __attribute__((ext_vector_type(4))) float f32x4;

__device__ __forceinline__ float2 upk(u32 u) {
    __half2 h = *reinterpret_cast<__half2*>(&u);
    return __half22float2(h);
}
__device__ __forceinline__ u32 pk2(float x, float y) {
    __half2 h = __floats2half2_rn(x, y);
    return *reinterpret_cast<u32*>(&h);
}

// ---- pass 1: bin edges by dst into bucket arrays (LDS-staged) -----------
__global__ __launch_bounds__(256) void k_bin(const int* __restrict__ src, const int* __restrict__ dst,
                                             u32* __restrict__ gbuf, int* __restrict__ gcur, int E) {
    __shared__ u32 lst[NBK][BIN_CAP];
    __shared__ int lcnt[NBK];
    __shared__ int lbase[NBK];
    int tid = threadIdx.x;
    for (int i = tid; i < NBK; i += 256) lcnt[i] = 0;
    __syncthreads();
    int beg = blockIdx.x * BCHUNK;
    int end = min(beg + BCHUNK, E);
    for (int e = beg + tid; e < end; e += 256) {
        int d = dst[e];
        u32 u = (u32)src[e] | ((u32)(d & (BINW - 1)) << 17);
        int b = d >> 9;
        int p = atomicAdd(&lcnt[b], 1);
        if (p < BIN_CAP) lst[b][p] = u;
        else {
            int gp = atomicAdd(&gcur[b], 1);
            if (gp < GCAP) gbuf[(size_t)b * GCAP + gp] = u;
        }
    }
    __syncthreads();
    for (int b = tid; b < NBK; b += 256) {
        int c = min(lcnt[b], BIN_CAP);
        lbase[b] = atomicAdd(&gcur[b], c);
        lcnt[b] = c;
    }
    __syncthreads();
    int wid = tid >> 6, lane = tid & 63;
    for (int b = wid; b < NBK; b += 4) {
        int c = lcnt[b], base = lbase[b];
        for (int i = lane; i < c; i += 64)
            gbuf[(size_t)b * GCAP + base + i] = lst[b][i];
    }
}

// ---- CSR + bounds + wconv, one dispatch ---------------------------------
__global__ __launch_bounds__(512) void k_csr(const u32* __restrict__ gbuf, const int* __restrict__ gcur,
                                             int* __restrict__ rowptr, float* __restrict__ dinv,
                                             int* __restrict__ col, int N,
                                             const int* __restrict__ batch, int* __restrict__ gstart, int ngraphs,
                                             const float* __restrict__ W1, const float* __restrict__ W2,
                                             const float* __restrict__ W3, f16* __restrict__ Wpk) {
    int b = blockIdx.x, tid = threadIdx.x;
    if (b >= NBK) {                                 // ---- wconv blocks ----
        const float* Ws[3] = {W1, W2, W3};
        const float* W = Ws[b - NBK];
        int i = tid >> 6, l = tid & 63;
        int s = i & 1, t4 = i >> 1;
        int kbase = s * 32 + ((l >> 4) * 8);
        int cc = t4 * 16 + (l & 15);
        f16* dstp = Wpk + (((size_t)(b - NBK) * 8 + i) * 64 + l) * 8;
#pragma unroll
        for (int j = 0; j < 8; j++) dstp[j] = (f16)W[(kbase + j) * 64 + cc];
        return;
    }
    __shared__ int h[BINW];
    __shared__ int sc[BINW];
    __shared__ int bb[256];
    if (tid < 256) bb[tid] = (tid < NBK) ? min(gcur[tid], GCAP) : 0;
    __syncthreads();
    for (int o = 1; o < 256; o <<= 1) {
        int add = (tid < 256 && tid >= o) ? bb[tid - o] : 0;
        __syncthreads();
        if (tid < 256) bb[tid] += add;
        __syncthreads();
    }
    int my_base = (b == 0) ? 0 : bb[b - 1];
    if (b == 0 && tid == 0) rowptr[N] = bb[NBK - 1];
    h[tid] = 0;
    __syncthreads();
    int c = min(gcur[b], GCAP);
    const u32* p = gbuf + (size_t)b * GCAP;
    for (int i = tid; i < c; i += 512) atomicAdd(&h[p[i] >> 17], 1);
    __syncthreads();
    int cnt = h[tid];
    sc[tid] = cnt;
    __syncthreads();
    for (int o = 1; o < BINW; o <<= 1) {
        int add = (tid >= o) ? sc[tid - o] : 0;
        __syncthreads();
        sc[tid] += add;
        __syncthreads();
    }
    int ex = my_base + sc[tid] - cnt;
    int node = b * BINW + tid;
    if (node < N) {
        rowptr[node] = ex;
        dinv[node] = rsqrtf((float)(cnt + 1));     // degree includes self-loop
        int bat = batch[node];
        int prev = (node == 0) ? -1 : batch[node - 1];
        for (int g = prev + 1; g <= bat; g++) gstart[g] = node;
        if (node == N - 1) for (int g = bat + 1; g <= ngraphs; g++) gstart[g] = N;
    }
    h[tid] = ex;
    __syncthreads();
    for (int i = tid; i < c; i += 512) {
        u32 u = p[i];
        int pos = atomicAdd(&h[u >> 17], 1);
        col[pos] = (int)(u & 0x1FFFF);
    }
}

// ---- MFMA gemm, f32 input (layer 1): g = f16(dinv * (x @ W)) ------------
__global__ __launch_bounds__(256) void k_gmfma_x(const float* __restrict__ in, const f16x8* __restrict__ Wpk,
                                                 const float* __restrict__ dinv, f16* __restrict__ out, int n_nodes) {
    int lane = threadIdx.x & 63;
    int wv = blockIdx.x * 4 + (threadIdx.x >> 6);
    int ntiles = (n_nodes + 15) >> 4;
    if (wv >= ntiles) return;
    f16x8 bf[8];
#pragma unroll
    for (int i = 0; i < 8; i++) bf[i] = Wpk[i * 64 + lane];
    int r0 = lane & 15;
    int kc = (lane >> 4) * 8;
    int n0 = wv * 16;
    int ar = min(n0 + r0, n_nodes - 1);
    const float* arow = in + (size_t)ar * CH + kc;
    float4 p0 = *(const float4*)(arow);
    float4 p1 = *(const float4*)(arow + 4);
    float4 q0 = *(const float4*)(arow + 32);
    float4 q1 = *(const float4*)(arow + 36);
    float pa[8] = {p0.x, p0.y, p0.z, p0.w, p1.x, p1.y, p1.z, p1.w};
    float qa[8] = {q0.x, q0.y, q0.z, q0.w, q1.x, q1.y, q1.z, q1.w};
    f16x8 a0, a1;
#pragma unroll
    for (int j = 0; j < 8; j++) { a0[j] = (f16)pa[j]; a1[j] = (f16)qa[j]; }
    f32x4 z = {0.f, 0.f, 0.f, 0.f};
    f32x4 acc0 = z, acc1 = z, acc2 = z, acc3 = z;
    acc0 = __builtin_amdgcn_mfma_f32_16x16x32_f16(a0, bf[0], acc0, 0, 0, 0);
    acc0 = __builtin_amdgcn_mfma_f32_16x16x32_f16(a1, bf[1], acc0, 0, 0, 0);
    acc1 = __builtin_amdgcn_mfma_f32_16x16x32_f16(a0, bf[2], acc1, 0, 0, 0);
    acc1 = __builtin_amdgcn_mfma_f32_16x16x32_f16(a1, bf[3], acc1, 0, 0, 0);
    acc2 = __builtin_amdgcn_mfma_f32_16x16x32_f16(a0, bf[4], acc2, 0, 0, 0);
    acc2 = __builtin_amdgcn_mfma_f32_16x16x32_f16(a1, bf[5], acc2, 0, 0, 0);
    acc3 = __builtin_amdgcn_mfma_f32_16x16x32_f16(a0, bf[6], acc3, 0, 0, 0);
    acc3 = __builtin_amdgcn_mfma_f32_16x16x32_f16(a1, bf[7], acc3, 0, 0, 0);
    int rb = n0 + (lane >> 4) * 4;
    float4 dv = *(const float4*)(dinv + rb);
    float dva[4] = {dv.x, dv.y, dv.z, dv.w};
#pragma unroll
    for (int r = 0; r < 4; r++) {
        int nn = rb + r;
        if (nn < n_nodes) {
            f16* orow = out + (size_t)nn * CH + r0;
            orow[0]  = (f16)(acc0[r] * dva[r]);
            orow[16] = (f16)(acc1[r] * dva[r]);
            orow[32] = (f16)(acc2[r] * dva[r]);
            orow[48] = (f16)(acc3[r] * dva[r]);
        }
    }
}

// ---- MFMA gemm, f16 input: g = f16(dinv * (h @ W)) ----------------------
__global__ __launch_bounds__(256) void k_gmfma_h(const f16* __restrict__ in, const f16x8* __restrict__ Wpk,
                                                 const float* __restrict__ dinv, f16* __restrict__ out, int n_nodes) {
    int lane = threadIdx.x & 63;
    int wv = blockIdx.x * 4 + (threadIdx.x >> 6);
    int ntiles = (n_nodes + 15) >> 4;
    if (wv >= ntiles) return;
    f16x8 bf[8];
#pragma unroll
    for (int i = 0; i < 8; i++) bf[i] = Wpk[i * 64 + lane];
    int r0 = lane & 15;
    int kc = (lane >> 4) * 8;
    int n0 = wv * 16;
    int ar = min(n0 + r0, n_nodes - 1);
    const f16* arow = in + (size_t)ar * CH + kc;
    f16x8 a0 = *(const f16x8*)(arow);
    f16x8 a1 = *(const f16x8*)(arow + 32);
    f32x4 z = {0.f, 0.f, 0.f, 0.f};
    f32x4 acc0 = z, acc1 = z, acc2 = z, acc3 = z;
    acc0 = __builtin_amdgcn_mfma_f32_16x16x32_f16(a0, bf[0], acc0, 0, 0, 0);
    acc0 = __builtin_amdgcn_mfma_f32_16x16x32_f16(a1, bf[1], acc0, 0, 0, 0);
    acc1 = __builtin_amdgcn_mfma_f32_16x16x32_f16(a0, bf[2], acc1, 0, 0, 0);
    acc1 = __builtin_amdgcn_mfma_f32_16x16x32_f16(a1, bf[3], acc1, 0, 0, 0);
    acc2 = __builtin_amdgcn_mfma_f32_16x16x32_f16(a0, bf[4], acc2, 0, 0, 0);
    acc2 = __builtin_amdgcn_mfma_f32_16x16x32_f16(a1, bf[5], acc2, 0, 0, 0);
    acc3 = __builtin_amdgcn_mfma_f32_16x16x32_f16(a0, bf[6], acc3, 0, 0, 0);
    acc3 = __builtin_amdgcn_mfma_f32_16x16x32_f16(a1, bf[7], acc3, 0, 0, 0);
    int rb = n0 + (lane >> 4) * 4;
    float4 dv = *(const float4*)(dinv + rb);
    float dva[4] = {dv.x, dv.y, dv.z, dv.w};
#pragma unroll
    for (int r = 0; r < 4; r++) {
        int nn = rb + r;
        if (nn < n_nodes) {
            f16* orow = out + (size_t)nn * CH + r0;
            orow[0]  = (f16)(acc0[r] * dva[r]);
            orow[16] = (f16)(acc1[r] * dva[r]);
            orow[32] = (f16)(acc2[r] * dva[r]);
            orow[48] = (f16)(acc3[r] * dva[r]);
        }
    }
}

// ---- half-wave-per-node gather: paired dwordx2 + conditional half 2 -----
// Half-lane hl = (s = hl>>4, c4 = hl&15). Virtual rows: 0 = self, r>=1 ->
// col[beg+r-1]. Half 1 (8 paired loads) covers rows 0..15 always; half 2
// covers rows 16..31 only when nv > 16. shfl_xor(16) merges parities.
__global__ __launch_bounds__(512) void k_agg2(const u32* __restrict__ g, const int* __restrict__ rowptr,
                                              const int* __restrict__ col, const float* __restrict__ dinv,
                                              const float* __restrict__ bias, u32* __restrict__ h, int n_nodes) {
    int hl = threadIdx.x & 31;
    int s = hl >> 4;
    int c4 = hl & 15;
    int node = (blockIdx.x * 512 + threadIdx.x) >> 5;
    if (node >= n_nodes) return;
    int beg = rowptr[node], end = rowptr[node + 1];
    int deg = end - beg;
    int nv = min(deg + 1, 32);                       // virtual rows
    int vi = (hl == 0 || deg == 0) ? node : col[beg + min(hl, deg) - 1];
    float a0 = 0.f, a1 = 0.f, a2 = 0.f, a3 = 0.f;
    {   // half 1: rows 0..15
        u32 lo[8], hi[8];
#pragma unroll
        for (int t = 0; t < 8; t++) {
            int j = __shfl(vi, 2 * t + s, 32);
            uint2 v = *(const uint2*)(g + (size_t)j * 32 + c4 * 2);
            lo[t] = v.x; hi[t] = v.y;
        }
#pragma unroll
        for (int t = 0; t < 8; t++) {
            bool ok = (2 * t + s) < nv;
            float2 f0 = upk(ok ? lo[t] : 0u);
            float2 f1 = upk(ok ? hi[t] : 0u);
            a0 += f0.x; a1 += f0.y; a2 += f1.x; a3 += f1.y;
        }
    }
    if (nv > 16) {   // half 2: rows 16..31
        u32 lo[8], hi[8];
#pragma unroll
        for (int t = 0; t < 8; t++) {
            int j = __shfl(vi, 16 + 2 * t + s, 32);
            uint2 v = *(const uint2*)(g + (size_t)j * 32 + c4 * 2);
            lo[t] = v.x; hi[t] = v.y;
        }
#pragma unroll
        for (int t = 0; t < 8; t++) {
            bool ok = (16 + 2 * t + s) < nv;
            float2 f0 = upk(ok ? lo[t] : 0u);
            float2 f1 = upk(ok ? hi[t] : 0u);
            a0 += f0.x; a1 += f0.y; a2 += f1.x; a3 += f1.y;
        }
    }
    for (int i = 32; i <= deg; i++) {                // rare: deg > 31
        if (s == 0) {
            uint2 v = *(const uint2*)(g + (size_t)col[beg + i - 1] * 32 + c4 * 2);
            float2 f0 = upk(v.x), f1 = upk(v.y);
            a0 += f0.x; a1 += f0.y; a2 += f1.x; a3 += f1.y;
        }
    }
    a0 += __shfl_xor(a0, 16, 32);
    a1 += __shfl_xor(a1, 16, 32);
    a2 += __shfl_xor(a2, 16, 32);
    a3 += __shfl_xor(a3, 16, 32);
    if (s == 0) {
        float dn = dinv[node];
        float4 bb = *(const float4*)(bias + 4 * c4);
        uint2 wv;
        wv.x = pk2(fmaxf(fmaf(dn, a0, bb.x), 0.f), fmaxf(fmaf(dn, a1, bb.y), 0.f));
        wv.y = pk2(fmaxf(fmaf(dn, a2, bb.z), 0.f), fmaxf(fmaf(dn, a3, bb.w), 0.f));
        *(uint2*)(h + (size_t)node * 32 + c4 * 2) = wv;
    }
}

// ---- fused mean-pool + head: 512-thr block per graph --------------------
__global__ __launch_bounds__(512) void k_pool_head(const u32* __restrict__ h, const int* __restrict__ gstart,
                                                   const float* __restrict__ Wl, const float* __restrict__ bl,
                                                   float* __restrict__ out) {
    __shared__ float part[16][CH];
    __shared__ float mean[CH];
    int gg = blockIdx.x;
    int hw = threadIdx.x >> 5;
    int c2 = threadIdx.x & 31;
    int beg = gstart[gg], end = gstart[gg + 1];
    float a0 = 0.f, a1 = 0.f;
    for (int n = beg + hw; n < end; n += 16) {
        float2 f = upk(h[(size_t)n * 32 + c2]);
        a0 += f.x; a1 += f.y;
    }
    part[hw][2 * c2] = a0; part[hw][2 * c2 + 1] = a1;
    __syncthreads();
    if (threadIdx.x < CH) {
        int c = threadIdx.x;
        float s = 0.f;
#pragma unroll
        for (int i = 0; i < 16; i++) s += part[i][c];
        float inv = 1.0f / fmaxf((float)(end - beg), 1.0f);
        mean[c] = s * inv;
    }
    __syncthreads();
    if (threadIdx.x < OC) {
        int o = threadIdx.x;
        float a = bl[o];
#pragma unroll
        for (int c = 0; c < CH; c++) a = fmaf(mean[c], Wl[c * OC + o], a);
        out[gg * OC + o] = a;
    }
}

extern "C" void kernel_launch(void* const* d_in, const int* in_sizes, int n_in,
                              void* d_out, int out_size, void* d_ws, size_t ws_size,
                              hipStream_t stream) {
    const float* x    = (const float*)d_in[0];
    const int*   edge = (const int*)d_in[1];   // [2][E]: src then dst
    const int*   batch= (const int*)d_in[2];
    const float* W1 = (const float*)d_in[3]; const float* b1 = (const float*)d_in[4];
    const float* W2 = (const float*)d_in[5]; const float* b2 = (const float*)d_in[6];
    const float* W3 = (const float*)d_in[7]; const float* b3 = (const float*)d_in[8];
    const float* Wl = (const float*)d_in[9]; const float* bl = (const float*)d_in[10];
    float* out = (float*)d_out;

    const int N  = in_sizes[2];        // 100000 (<= 100352 for NBK=196)
    const int E  = in_sizes[1] / 2;    // 1600000
    const int NG = out_size / OC;      // 128
    const int* src = edge;
    const int* dst = edge + E;

    char* p = (char*)d_ws;
    auto alloc = [&](size_t bytes) -> void* { void* r = p; p += (bytes + 255) & ~(size_t)255; return r; };
    int*   rowptr = (int*)alloc((size_t)(N + 1) * 4);
    int*   col    = (int*)alloc((size_t)E * 4);
    float* dinv   = (float*)alloc((size_t)N * 4);
    int*   gstart = (int*)alloc((size_t)(NG + 1) * 4);
    int*   gcur   = (int*)alloc((size_t)NBK * 4);
    u32*   gbuf   = (u32*)alloc((size_t)NBK * GCAP * 4);
    f16*   Wpk    = (f16*)alloc((size_t)3 * 8 * 64 * 8 * 2);
    u32*   Ga     = (u32*)alloc((size_t)N * CH * 2);
    u32*   Hb     = (u32*)alloc((size_t)N * CH * 2);

    hipMemsetAsync(gcur, 0, (size_t)NBK * 4, stream);

    int nbl2 = (N * 32 + 511) / 512;               // half-wave per node
    int binb = (E + BCHUNK - 1) / BCHUNK;
    int gemb = ((N + 15) / 16 + 3) / 4;            // 4 tiles/block

    k_bin<<<binb, 256, 0, stream>>>(src, dst, gbuf, gcur, E);
    k_csr<<<NBK + 3, 512, 0, stream>>>(gbuf, gcur, rowptr, dinv, col, N,
                                       batch, gstart, NG, W1, W2, W3, Wpk);

    const f16x8* Wp = (const f16x8*)Wpk;
    k_gmfma_x<<<gemb, 256, 0, stream>>>(x, Wp, dinv, (f16*)Ga, N);                     // g1
    k_agg2<<<nbl2, 512, 0, stream>>>(Ga, rowptr, col, dinv, b1, Hb, N);                // h1
    k_gmfma_h<<<gemb, 256, 0, stream>>>((const f16*)Hb, Wp + 8 * 64, dinv, (f16*)Ga, N);   // g2
    k_agg2<<<nbl2, 512, 0, stream>>>(Ga, rowptr, col, dinv, b2, Hb, N);                // h2
    k_gmfma_h<<<gemb, 256, 0, stream>>>((const f16*)Hb, Wp + 16 * 64, dinv, (f16*)Ga, N);  // g3
    k_agg2<<<nbl2, 512, 0, stream>>>(Ga, rowptr, col, dinv, b3, Hb, N);                // h3
    k_pool_head<<<NG, 512, 0, stream>>>(Hb, gstart, Wl, bl, out);
}

// Round 14
// 188.863 us; speedup vs baseline: 1.0235x; 1.0218x over previous
//
#include <hip/hip_runtime.h>
#include <hip/hip_fp16.h>

// GCN: 3x GCNConv(relu) + global_mean_pool + linear head.
//   k_bin:  bucket edges by dst (LDS-staged, BCHUNK=4096).
//   k_csr:  bucket-total scan + histogram + LDS scan -> rowptr/dinv + place
//           + fused k_bounds + fused wconv (blocks 196..198).
//   k_gmfma_x/h: g = f16(dinv*(in@W)) via mfma_f32_16x16x32_f16.
//   k_agg2: half-wave-per-node gather (R11 scheme -- best measured):
//           clamped vector index fetch, one-row-per-load-instruction dword
//           gathers, masked fixed 16-deep batch + conditional second batch.
//           R12/R13 A/B/A showed paired dwordx2 (2 rows/instr) is ~3.5us
//           WORSE: 4 line-segments from 2 random rows per instr coalesce
//           worse than 32-lane single-row. Bytes, not instr count, bind.
// Pool: 512-thr block-per-graph segmented mean + fused 64x32 head.

#define CH 64
#define OC 32

#define BINW 512
#define NBK  196         // ceil(100000/512); valid for N <= 100352
#define BIN_CAP 56       // mean 4096/196 = 20.9 per bucket per chunk
#define BCHUNK 4096
#define GCAP 10240       // per-bucket cap (mean 8163, +23 sigma)

typedef unsigned int u32;
typedef _Float16 f16;
typedef __attribute__((ext_vector_type(8))) _Float16 f16x8;
typedef __attribute__((ext_vector_type(4))) float f32x4;

__device__ __forceinline__ float2 upk(u32 u) {
    __half2 h = *reinterpret_cast<__half2*>(&u);
    return __half22float2(h);
}
__device__ __forceinline__ u32 pk2(float x, float y) {
    __half2 h = __floats2half2_rn(x, y);
    return *reinterpret_cast<u32*>(&h);
}

// ---- pass 1: bin edges by dst into bucket arrays (LDS-staged) -----------
__global__ __launch_bounds__(256) void k_bin(const int* __restrict__ src, const int* __restrict__ dst,
                                             u32* __restrict__ gbuf, int* __restrict__ gcur, int E) {
    __shared__ u32 lst[NBK][BIN_CAP];
    __shared__ int lcnt[NBK];
    __shared__ int lbase[NBK];
    int tid = threadIdx.x;
    for (int i = tid; i < NBK; i += 256) lcnt[i] = 0;
    __syncthreads();
    int beg = blockIdx.x * BCHUNK;
    int end = min(beg + BCHUNK, E);
    for (int e = beg + tid; e < end; e += 256) {
        int d = dst[e];
        u32 u = (u32)src[e] | ((u32)(d & (BINW - 1)) << 17);
        int b = d >> 9;
        int p = atomicAdd(&lcnt[b], 1);
        if (p < BIN_CAP) lst[b][p] = u;
        else {
            int gp = atomicAdd(&gcur[b], 1);
            if (gp < GCAP) gbuf[(size_t)b * GCAP + gp] = u;
        }
    }
    __syncthreads();
    for (int b = tid; b < NBK; b += 256) {
        int c = min(lcnt[b], BIN_CAP);
        lbase[b] = atomicAdd(&gcur[b], c);
        lcnt[b] = c;
    }
    __syncthreads();
    int wid = tid >> 6, lane = tid & 63;
    for (int b = wid; b < NBK; b += 4) {
        int c = lcnt[b], base = lbase[b];
        for (int i = lane; i < c; i += 64)
            gbuf[(size_t)b * GCAP + base + i] = lst[b][i];
    }
}

// ---- CSR + bounds + wconv, one dispatch ---------------------------------
__global__ __launch_bounds__(512) void k_csr(const u32* __restrict__ gbuf, const int* __restrict__ gcur,
                                             int* __restrict__ rowptr, float* __restrict__ dinv,
                                             int* __restrict__ col, int N,
                                             const int* __restrict__ batch, int* __restrict__ gstart, int ngraphs,
                                             const float* __restrict__ W1, const float* __restrict__ W2,
                                             const float* __restrict__ W3, f16* __restrict__ Wpk) {
    int b = blockIdx.x, tid = threadIdx.x;
    if (b >= NBK) {                                 // ---- wconv blocks ----
        const float* Ws[3] = {W1, W2, W3};
        const float* W = Ws[b - NBK];
        int i = tid >> 6, l = tid & 63;
        int s = i & 1, t4 = i >> 1;
        int kbase = s * 32 + ((l >> 4) * 8);
        int cc = t4 * 16 + (l & 15);
        f16* dstp = Wpk + (((size_t)(b - NBK) * 8 + i) * 64 + l) * 8;
#pragma unroll
        for (int j = 0; j < 8; j++) dstp[j] = (f16)W[(kbase + j) * 64 + cc];
        return;
    }
    __shared__ int h[BINW];
    __shared__ int sc[BINW];
    __shared__ int bb[256];
    if (tid < 256) bb[tid] = (tid < NBK) ? min(gcur[tid], GCAP) : 0;
    __syncthreads();
    for (int o = 1; o < 256; o <<= 1) {
        int add = (tid < 256 && tid >= o) ? bb[tid - o] : 0;
        __syncthreads();
        if (tid < 256) bb[tid] += add;
        __syncthreads();
    }
    int my_base = (b == 0) ? 0 : bb[b - 1];
    if (b == 0 && tid == 0) rowptr[N] = bb[NBK - 1];
    h[tid] = 0;
    __syncthreads();
    int c = min(gcur[b], GCAP);
    const u32* p = gbuf + (size_t)b * GCAP;
    for (int i = tid; i < c; i += 512) atomicAdd(&h[p[i] >> 17], 1);
    __syncthreads();
    int cnt = h[tid];
    sc[tid] = cnt;
    __syncthreads();
    for (int o = 1; o < BINW; o <<= 1) {
        int add = (tid >= o) ? sc[tid - o] : 0;
        __syncthreads();
        sc[tid] += add;
        __syncthreads();
    }
    int ex = my_base + sc[tid] - cnt;
    int node = b * BINW + tid;
    if (node < N) {
        rowptr[node] = ex;
        dinv[node] = rsqrtf((float)(cnt + 1));     // degree includes self-loop
        int bat = batch[node];
        int prev = (node == 0) ? -1 : batch[node - 1];
        for (int g = prev + 1; g <= bat; g++) gstart[g] = node;
        if (node == N - 1) for (int g = bat + 1; g <= ngraphs; g++) gstart[g] = N;
    }
    h[tid] = ex;
    __syncthreads();
    for (int i = tid; i < c; i += 512) {
        u32 u = p[i];
        int pos = atomicAdd(&h[u >> 17], 1);
        col[pos] = (int)(u & 0x1FFFF);
    }
}

// ---- MFMA gemm, f32 input (layer 1): g = f16(dinv * (x @ W)) ------------
__global__ __launch_bounds__(256) void k_gmfma_x(const float* __restrict__ in, const f16x8* __restrict__ Wpk,
                                                 const float* __restrict__ dinv, f16* __restrict__ out, int n_nodes) {
    int lane = threadIdx.x & 63;
    int wv = blockIdx.x * 4 + (threadIdx.x >> 6);
    int ntiles = (n_nodes + 15) >> 4;
    if (wv >= ntiles) return;
    f16x8 bf[8];
#pragma unroll
    for (int i = 0; i < 8; i++) bf[i] = Wpk[i * 64 + lane];
    int r0 = lane & 15;
    int kc = (lane >> 4) * 8;
    int n0 = wv * 16;
    int ar = min(n0 + r0, n_nodes - 1);
    const float* arow = in + (size_t)ar * CH + kc;
    float4 p0 = *(const float4*)(arow);
    float4 p1 = *(const float4*)(arow + 4);
    float4 q0 = *(const float4*)(arow + 32);
    float4 q1 = *(const float4*)(arow + 36);
    float pa[8] = {p0.x, p0.y, p0.z, p0.w, p1.x, p1.y, p1.z, p1.w};
    float qa[8] = {q0.x, q0.y, q0.z, q0.w, q1.x, q1.y, q1.z, q1.w};
    f16x8 a0, a1;
#pragma unroll
    for (int j = 0; j < 8; j++) { a0[j] = (f16)pa[j]; a1[j] = (f16)qa[j]; }
    f32x4 z = {0.f, 0.f, 0.f, 0.f};
    f32x4 acc0 = z, acc1 = z, acc2 = z, acc3 = z;
    acc0 = __builtin_amdgcn_mfma_f32_16x16x32_f16(a0, bf[0], acc0, 0, 0, 0);
    acc0 = __builtin_amdgcn_mfma_f32_16x16x32_f16(a1, bf[1], acc0, 0, 0, 0);
    acc1 = __builtin_amdgcn_mfma_f32_16x16x32_f16(a0, bf[2], acc1, 0, 0, 0);
    acc1 = __builtin_amdgcn_mfma_f32_16x16x32_f16(a1, bf[3], acc1, 0, 0, 0);
    acc2 = __builtin_amdgcn_mfma_f32_16x16x32_f16(a0, bf[4], acc2, 0, 0, 0);
    acc2 = __builtin_amdgcn_mfma_f32_16x16x32_f16(a1, bf[5], acc2, 0, 0, 0);
    acc3 = __builtin_amdgcn_mfma_f32_16x16x32_f16(a0, bf[6], acc3, 0, 0, 0);
    acc3 = __builtin_amdgcn_mfma_f32_16x16x32_f16(a1, bf[7], acc3, 0, 0, 0);
    int rb = n0 + (lane >> 4) * 4;
    float4 dv = *(const float4*)(dinv + rb);
    float dva[4] = {dv.x, dv.y, dv.z, dv.w};
#pragma unroll
    for (int r = 0; r < 4; r++) {
        int nn = rb + r;
        if (nn < n_nodes) {
            f16* orow = out + (size_t)nn * CH + r0;
            orow[0]  = (f16)(acc0[r] * dva[r]);
            orow[16] = (f16)(acc1[r] * dva[r]);
            orow[32] = (f16)(acc2[r] * dva[r]);
            orow[48] = (f16)(acc3[r] * dva[r]);
        }
    }
}

// ---- MFMA gemm, f16 input: g = f16(dinv * (h @ W)) ----------------------
__global__ __launch_bounds__(256) void k_gmfma_h(const f16* __restrict__ in, const f16x8* __restrict__ Wpk,
                                                 const float* __restrict__ dinv, f16* __restrict__ out, int n_nodes) {
    int lane = threadIdx.x & 63;
    int wv = blockIdx.x * 4 + (threadIdx.x >> 6);
    int ntiles = (n_nodes + 15) >> 4;
    if (wv >= ntiles) return;
    f16x8 bf[8];
#pragma unroll
    for (int i = 0; i < 8; i++) bf[i] = Wpk[i * 64 + lane];
    int r0 = lane & 15;
    int kc = (lane >> 4) * 8;
    int n0 = wv * 16;
    int ar = min(n0 + r0, n_nodes - 1);
    const f16* arow = in + (size_t)ar * CH + kc;
    f16x8 a0 = *(const f16x8*)(arow);
    f16x8 a1 = *(const f16x8*)(arow + 32);
    f32x4 z = {0.f, 0.f, 0.f, 0.f};
    f32x4 acc0 = z, acc1 = z, acc2 = z, acc3 = z;
    acc0 = __builtin_amdgcn_mfma_f32_16x16x32_f16(a0, bf[0], acc0, 0, 0, 0);
    acc0 = __builtin_amdgcn_mfma_f32_16x16x32_f16(a1, bf[1], acc0, 0, 0, 0);
    acc1 = __builtin_amdgcn_mfma_f32_16x16x32_f16(a0, bf[2], acc1, 0, 0, 0);
    acc1 = __builtin_amdgcn_mfma_f32_16x16x32_f16(a1, bf[3], acc1, 0, 0, 0);
    acc2 = __builtin_amdgcn_mfma_f32_16x16x32_f16(a0, bf[4], acc2, 0, 0, 0);
    acc2 = __builtin_amdgcn_mfma_f32_16x16x32_f16(a1, bf[5], acc2, 0, 0, 0);
    acc3 = __builtin_amdgcn_mfma_f32_16x16x32_f16(a0, bf[6], acc3, 0, 0, 0);
    acc3 = __builtin_amdgcn_mfma_f32_16x16x32_f16(a1, bf[7], acc3, 0, 0, 0);
    int rb = n0 + (lane >> 4) * 4;
    float4 dv = *(const float4*)(dinv + rb);
    float dva[4] = {dv.x, dv.y, dv.z, dv.w};
#pragma unroll
    for (int r = 0; r < 4; r++) {
        int nn = rb + r;
        if (nn < n_nodes) {
            f16* orow = out + (size_t)nn * CH + r0;
            orow[0]  = (f16)(acc0[r] * dva[r]);
            orow[16] = (f16)(acc1[r] * dva[r]);
            orow[32] = (f16)(acc2[r] * dva[r]);
            orow[48] = (f16)(acc3[r] * dva[r]);
        }
    }
}

// ---- half-wave-per-node gather: two masked 16-deep batches (R11) --------
// Indices clamped at fetch: lane i>=nb duplicates the last neighbor (same
// 128B line -> L1 hit), its contribution masked to 0. 1-2 exposed latencies.
__global__ __launch_bounds__(512) void k_agg2(const u32* __restrict__ g, const int* __restrict__ rowptr,
                                              const int* __restrict__ col, const float* __restrict__ dinv,
                                              const float* __restrict__ bias, u32* __restrict__ h, int n_nodes) {
    int c2 = threadIdx.x & 31;
    int node = (blockIdx.x * 512 + threadIdx.x) >> 5;
    if (node >= n_nodes) return;
    int beg = rowptr[node], end = rowptr[node + 1];
    int deg = end - beg;
    float2 sf = upk(g[(size_t)node * 32 + c2]);       // self row
    float a0 = sf.x, a1 = sf.y;
    int nb = min(deg, 32);
    int jv = (nb > 0) ? col[beg + min(c2, nb - 1)] : 0;   // clamped vector fetch
    if (nb > 0) {
        {   // batch 0: neighbors 0..15 (masked)
            u32 uu[16];
#pragma unroll
            for (int i = 0; i < 16; i++) {
                int j = __shfl(jv, i, 32);
                uu[i] = g[(size_t)j * 32 + c2];
            }
#pragma unroll
            for (int i = 0; i < 16; i++) {
                u32 v = (i < nb) ? uu[i] : 0u;
                float2 f = upk(v);
                a0 += f.x; a1 += f.y;
            }
        }
        if (nb > 16) {   // batch 1: neighbors 16..31 (masked)
            u32 uu[16];
#pragma unroll
            for (int i = 0; i < 16; i++) {
                int j = __shfl(jv, 16 + i, 32);
                uu[i] = g[(size_t)j * 32 + c2];
            }
#pragma unroll
            for (int i = 0; i < 16; i++) {
                u32 v = (16 + i < nb) ? uu[i] : 0u;
                float2 f = upk(v);
                a0 += f.x; a1 += f.y;
            }
        }
    }
    for (int k = beg + 32; k < end; k++) {            // rare: deg > 32
        float2 f = upk(g[(size_t)col[k] * 32 + c2]);
        a0 += f.x; a1 += f.y;
    }
    float dn = dinv[node];
    float2 bb = *(const float2*)(bias + 2 * c2);
    float h0 = fmaxf(fmaf(dn, a0, bb.x), 0.f);
    float h1 = fmaxf(fmaf(dn, a1, bb.y), 0.f);
    h[(size_t)node * 32 + c2] = pk2(h0, h1);
}

// ---- fused mean-pool + head: 512-thr block per graph --------------------
__global__ __launch_bounds__(512) void k_pool_head(const u32* __restrict__ h, const int* __restrict__ gstart,
                                                   const float* __restrict__ Wl, const float* __restrict__ bl,
                                                   float* __restrict__ out) {
    __shared__ float part[16][CH];
    __shared__ float mean[CH];
    int gg = blockIdx.x;
    int hw = threadIdx.x >> 5;
    int c2 = threadIdx.x & 31;
    int beg = gstart[gg], end = gstart[gg + 1];
    float a0 = 0.f, a1 = 0.f;
    for (int n = beg + hw; n < end; n += 16) {
        float2 f = upk(h[(size_t)n * 32 + c2]);
        a0 += f.x; a1 += f.y;
    }
    part[hw][2 * c2] = a0; part[hw][2 * c2 + 1] = a1;
    __syncthreads();
    if (threadIdx.x < CH) {
        int c = threadIdx.x;
        float s = 0.f;
#pragma unroll
        for (int i = 0; i < 16; i++) s += part[i][c];
        float inv = 1.0f / fmaxf((float)(end - beg), 1.0f);
        mean[c] = s * inv;
    }
    __syncthreads();
    if (threadIdx.x < OC) {
        int o = threadIdx.x;
        float a = bl[o];
#pragma unroll
        for (int c = 0; c < CH; c++) a = fmaf(mean[c], Wl[c * OC + o], a);
        out[gg * OC + o] = a;
    }
}

extern "C" void kernel_launch(void* const* d_in, const int* in_sizes, int n_in,
                              void* d_out, int out_size, void* d_ws, size_t ws_size,
                              hipStream_t stream) {
    const float* x    = (const float*)d_in[0];
    const int*   edge = (const int*)d_in[1];   // [2][E]: src then dst
    const int*   batch= (const int*)d_in[2];
    const float* W1 = (const float*)d_in[3]; const float* b1 = (const float*)d_in[4];
    const float* W2 = (const float*)d_in[5]; const float* b2 = (const float*)d_in[6];
    const float* W3 = (const float*)d_in[7]; const float* b3 = (const float*)d_in[8];
    const float* Wl = (const float*)d_in[9]; const float* bl = (const float*)d_in[10];
    float* out = (float*)d_out;

    const int N  = in_sizes[2];        // 100000 (<= 100352 for NBK=196)
    const int E  = in_sizes[1] / 2;    // 1600000
    const int NG = out_size / OC;      // 128
    const int* src = edge;
    const int* dst = edge + E;

    char* p = (char*)d_ws;
    auto alloc = [&](size_t bytes) -> void* { void* r = p; p += (bytes + 255) & ~(size_t)255; return r; };
    int*   rowptr = (int*)alloc((size_t)(N + 1) * 4);
    int*   col    = (int*)alloc((size_t)E * 4);
    float* dinv   = (float*)alloc((size_t)N * 4);
    int*   gstart = (int*)alloc((size_t)(NG + 1) * 4);
    int*   gcur   = (int*)alloc((size_t)NBK * 4);
    u32*   gbuf   = (u32*)alloc((size_t)NBK * GCAP * 4);
    f16*   Wpk    = (f16*)alloc((size_t)3 * 8 * 64 * 8 * 2);
    u32*   Ga     = (u32*)alloc((size_t)N * CH * 2);
    u32*   Hb     = (u32*)alloc((size_t)N * CH * 2);

    hipMemsetAsync(gcur, 0, (size_t)NBK * 4, stream);

    int nbl2 = (N * 32 + 511) / 512;               // half-wave per node
    int binb = (E + BCHUNK - 1) / BCHUNK;
    int gemb = ((N + 15) / 16 + 3) / 4;            // 4 tiles/block

    k_bin<<<binb, 256, 0, stream>>>(src, dst, gbuf, gcur, E);
    k_csr<<<NBK + 3, 512, 0, stream>>>(gbuf, gcur, rowptr, dinv, col, N,
                                       batch, gstart, NG, W1, W2, W3, Wpk);

    const f16x8* Wp = (const f16x8*)Wpk;
    k_gmfma_x<<<gemb, 256, 0, stream>>>(x, Wp, dinv, (f16*)Ga, N);                     // g1
    k_agg2<<<nbl2, 512, 0, stream>>>(Ga, rowptr, col, dinv, b1, Hb, N);                // h1
    k_gmfma_h<<<gemb, 256, 0, stream>>>((const f16*)Hb, Wp + 8 * 64, dinv, (f16*)Ga, N);   // g2
    k_agg2<<<nbl2, 512, 0, stream>>>(Ga, rowptr, col, dinv, b2, Hb, N);                // h2
    k_gmfma_h<<<gemb, 256, 0, stream>>>((const f16*)Hb, Wp + 16 * 64, dinv, (f16*)Ga, N);  // g3
    k_agg2<<<nbl2, 512, 0, stream>>>(Ga, rowptr, col, dinv, b3, Hb, N);                // h3
    k_pool_head<<<NG, 512, 0, stream>>>(Hb, gstart, Wl, bl, out);
}